// Round 2
// baseline (426.645 us; speedup 1.0000x reference)
//
#include <hip/hip_runtime.h>

// Problem constants: B=4, L=256, E=128, H=8, D=16, NU=512, NT=256. All I/O fp32.

// out[m, e] = sum_k x[m, k] * W[(w_row_off + e), k] + bias[e]
// W is [*, 128] (or [*,384] via w_ld) row-major fp32. grid = M blocks, 128 threads.
__global__ void proj_kernel(const float* __restrict__ x, int x_ld, int Kdim,
                            const float* __restrict__ W, int w_row_off,
                            const float* __restrict__ bias,
                            float* __restrict__ out)
{
    __shared__ float xs[128];
    int m = blockIdx.x;
    int e = threadIdx.x;  // 0..127
    if (e < Kdim) xs[e] = x[(size_t)m * x_ld + e];
    __syncthreads();
    const float* wrow = W + (size_t)(w_row_off + e) * 128;
    float acc = bias[e];
#pragma unroll 8
    for (int k = 0; k < Kdim; ++k) acc += xs[k] * wrow[k];
    out[(size_t)m * 128 + e] = acc;
}

// Standard MHA core for N=256 keys, 8 heads, D=16. One block (256 thr) per (b,l).
__global__ void attn256_kernel(const float* __restrict__ q, const float* __restrict__ kbuf,
                               const float* __restrict__ vbuf, float* __restrict__ o)
{
    int bl = blockIdx.x;          // b*L + l, L=256
    int b  = bl >> 8;
    int tid = threadIdx.x;
    __shared__ float qs[128];
    __shared__ float sc[8 * 256];
    __shared__ float hden[8];
    if (tid < 128) qs[tid] = q[(size_t)bl * 128 + tid];
    __syncthreads();

    // scores: thread = key n
    {
        int n = tid;
        const float* krow = kbuf + ((size_t)b * 256 + n) * 128;
#pragma unroll
        for (int h = 0; h < 8; ++h) {
            float acc = 0.f;
#pragma unroll
            for (int d = 0; d < 16; ++d) acc += qs[h * 16 + d] * krow[h * 16 + d];
            sc[h * 256 + n] = acc * 0.25f;   // 1/sqrt(16)
        }
    }
    __syncthreads();

    // per-head softmax: 32 lanes per head
    int h = tid >> 5, j = tid & 31;
    float mx = -1e30f;
    for (int n = j; n < 256; n += 32) mx = fmaxf(mx, sc[h * 256 + n]);
    for (int off = 16; off; off >>= 1) mx = fmaxf(mx, __shfl_down(mx, off, 32));
    mx = __shfl(mx, 0, 32);
    float p = 0.f;
    for (int n = j; n < 256; n += 32) {
        float ev = __expf(sc[h * 256 + n] - mx);
        sc[h * 256 + n] = ev;
        p += ev;
    }
    for (int off = 16; off; off >>= 1) p += __shfl_down(p, off, 32);
    if (j == 0) hden[h] = p;
    __syncthreads();

    // output: pair of threads per (h,d)
    int pr = tid >> 1, half = tid & 1;     // pr in [0,128)
    int hh = pr >> 4, dd = pr & 15;
    const float* vcol = vbuf + (size_t)b * 256 * 128 + hh * 16 + dd;
    float acc = 0.f;
    for (int n = half * 128; n < half * 128 + 128; ++n)
        acc += sc[hh * 256 + n] * vcol[(size_t)n * 128];
    acc += __shfl_down(acc, 1, 64);
    if (half == 0) o[(size_t)bl * 128 + pr] = acc / hden[hh];
}

// UU2DU attention: N=512 keys. Kbase/Vbase are the l-independent projections of
// [UUMat | 0 0]; the ci pair (cols 126/127 of Wk/Wv) enters as a rank-2 correction.
__global__ void attn_uu_kernel(const float* __restrict__ qd, const float* __restrict__ kbase,
                               const float* __restrict__ vbase, const float* __restrict__ CIMat,
                               const float* __restrict__ in_w, float* __restrict__ o)
{
    int bl = blockIdx.x;          // b*L + l
    int b = bl >> 8, l = bl & 255;
    int tid = threadIdx.x;
    __shared__ float qs[128];
    __shared__ float sc[8 * 512];
    __shared__ float ci0s[512], ci1s[512];
    __shared__ float qk126[8], qk127[8];
    __shared__ float hden[8], hs0[8], hs1[8];

    if (tid < 128) qs[tid] = qd[(size_t)bl * 128 + tid];
    __syncthreads();
    if (tid < 8) {
        float a = 0.f, c = 0.f;
#pragma unroll
        for (int d = 0; d < 16; ++d) {
            float qv = qs[tid * 16 + d];
            a += qv * in_w[(size_t)(128 + tid * 16 + d) * 128 + 126];
            c += qv * in_w[(size_t)(128 + tid * 16 + d) * 128 + 127];
        }
        qk126[tid] = a; qk127[tid] = c;
    }
    // ci0 = CIMat[b,n,l]; ci1 = CIMat[b,n,L+l]; CIMat is [4,512,512]
    for (int n = tid; n < 512; n += 256) {
        ci0s[n] = CIMat[((size_t)b * 512 + n) * 512 + l];
        ci1s[n] = CIMat[((size_t)b * 512 + n) * 512 + 256 + l];
    }
    __syncthreads();

    // scores
    for (int n = tid; n < 512; n += 256) {
        const float* krow = kbase + ((size_t)b * 512 + n) * 128;
        float c0 = ci0s[n], c1 = ci1s[n];
#pragma unroll
        for (int h = 0; h < 8; ++h) {
            float acc = c0 * qk126[h] + c1 * qk127[h];
#pragma unroll
            for (int d = 0; d < 16; ++d) acc += qs[h * 16 + d] * krow[h * 16 + d];
            sc[h * 512 + n] = acc * 0.25f;
        }
    }
    __syncthreads();

    // per-head softmax over 512 + weighted ci sums
    int h = tid >> 5, j = tid & 31;
    float mx = -1e30f;
    for (int n = j; n < 512; n += 32) mx = fmaxf(mx, sc[h * 512 + n]);
    for (int off = 16; off; off >>= 1) mx = fmaxf(mx, __shfl_down(mx, off, 32));
    mx = __shfl(mx, 0, 32);
    float p = 0.f, s0 = 0.f, s1 = 0.f;
    for (int n = j; n < 512; n += 32) {
        float ev = __expf(sc[h * 512 + n] - mx);
        sc[h * 512 + n] = ev;
        p += ev; s0 += ev * ci0s[n]; s1 += ev * ci1s[n];
    }
    for (int off = 16; off; off >>= 1) {
        p  += __shfl_down(p, off, 32);
        s0 += __shfl_down(s0, off, 32);
        s1 += __shfl_down(s1, off, 32);
    }
    if (j == 0) { hden[h] = p; hs0[h] = s0; hs1[h] = s1; }
    __syncthreads();

    // output: o[h,d] = (sum_n e*Vbase + s0*wv126 + s1*wv127) / den
    int pr = tid >> 1, half = tid & 1;
    int hh = pr >> 4;
    const float* vcol = vbase + (size_t)b * 512 * 128 + pr;
    float acc = 0.f;
    for (int n = half * 256; n < half * 256 + 256; ++n)
        acc += sc[hh * 512 + n] * vcol[(size_t)n * 128];
    acc += __shfl_down(acc, 1, 64);
    if (half == 0) {
        float wv126 = in_w[(size_t)(256 + pr) * 128 + 126];
        float wv127 = in_w[(size_t)(256 + pr) * 128 + 127];
        o[(size_t)bl * 128 + pr] = (acc + hs0[hh] * wv126 + hs1[hh] * wv127) / hden[hh];
    }
}

// y[m, e] = sum_{j<384} cat[m, j] * dim_w[e, j] + dim_b[e];  dim_w is [128, 384]
__global__ void dimproj_kernel(const float* __restrict__ p_uu, const float* __restrict__ p_ta,
                               const float* __restrict__ p_du,
                               const float* __restrict__ dim_w, const float* __restrict__ dim_b,
                               float* __restrict__ y)
{
    __shared__ float xs[384];
    int m = blockIdx.x;
    int e = threadIdx.x;  // 128
    xs[e]       = p_uu[(size_t)m * 128 + e];
    xs[128 + e] = p_ta[(size_t)m * 128 + e];
    xs[256 + e] = p_du[(size_t)m * 128 + e];
    __syncthreads();
    const float* wrow = dim_w + (size_t)e * 384;
    float acc = dim_b[e];
#pragma unroll 8
    for (int k = 0; k < 384; ++k) acc += xs[k] * wrow[k];
    y[(size_t)m * 128 + e] = acc;
}

// BatchNorm1d (training-mode batch stats over B*L=1024 samples per channel) + ReLU
__global__ void bn_kernel(const float* __restrict__ y, const float* __restrict__ gamma,
                          const float* __restrict__ beta, float* __restrict__ out)
{
    int e = blockIdx.x;     // channel, 128 blocks
    int tid = threadIdx.x;  // 256
    __shared__ float red[256], red2[256];
    float s = 0.f, s2 = 0.f;
    for (int m = tid; m < 1024; m += 256) {
        float v = y[(size_t)m * 128 + e];
        s += v; s2 += v * v;
    }
    red[tid] = s; red2[tid] = s2;
    __syncthreads();
    for (int off = 128; off; off >>= 1) {
        if (tid < off) { red[tid] += red[tid + off]; red2[tid] += red2[tid + off]; }
        __syncthreads();
    }
    float mean = red[0] * (1.f / 1024.f);
    float var  = red2[0] * (1.f / 1024.f) - mean * mean;
    float inv  = rsqrtf(var + 1e-5f);
    float g = gamma[e], bt = beta[e];
    for (int m = tid; m < 1024; m += 256) {
        float v = (y[(size_t)m * 128 + e] - mean) * inv * g + bt;
        out[(size_t)m * 128 + e] = fmaxf(v, 0.f);
    }
}

extern "C" void kernel_launch(void* const* d_in, const int* in_sizes, int n_in,
                              void* d_out, int out_size, void* d_ws, size_t ws_size,
                              hipStream_t stream)
{
    (void)in_sizes; (void)n_in; (void)out_size; (void)ws_size;
    const float* UUMat    = (const float*)d_in[0];   // [4,512,126]
    const float* DUMat    = (const float*)d_in[1];   // [4,256,128]
    const float* TAMat    = (const float*)d_in[2];   // [4,256,128]
    const float* CIMat    = (const float*)d_in[3];   // [4,512,512]
    const float* uu_in_w  = (const float*)d_in[4];   // [384,128]
    const float* uu_in_b  = (const float*)d_in[5];
    const float* uu_out_w = (const float*)d_in[6];   // [128,128]
    const float* uu_out_b = (const float*)d_in[7];
    const float* ta_in_w  = (const float*)d_in[8];
    const float* ta_in_b  = (const float*)d_in[9];
    const float* ta_out_w = (const float*)d_in[10];
    const float* ta_out_b = (const float*)d_in[11];
    const float* du_in_w  = (const float*)d_in[12];
    const float* du_in_b  = (const float*)d_in[13];
    const float* du_out_w = (const float*)d_in[14];
    const float* du_out_b = (const float*)d_in[15];
    const float* dim_w    = (const float*)d_in[16];  // [128,384]
    const float* dim_b    = (const float*)d_in[17];
    const float* bn_g     = (const float*)d_in[18];
    const float* bn_b     = (const float*)d_in[19];
    float* out = (float*)d_out;

    const int BL = 4 * 256;   // 1024 query rows
    const int BN = 4 * 512;   // 2048 UU rows
    float* ws = (float*)d_ws;
    float* qd    = ws; ws += (size_t)BL * 128;
    float* kbase = ws; ws += (size_t)BN * 128;
    float* vbase = ws; ws += (size_t)BN * 128;
    float* qta   = ws; ws += (size_t)BL * 128;
    float* kta   = ws; ws += (size_t)BL * 128;
    float* vta   = ws; ws += (size_t)BL * 128;
    float* qdu   = ws; ws += (size_t)BL * 128;
    float* kdu   = ws; ws += (size_t)BL * 128;
    float* vdu   = ws; ws += (size_t)BL * 128;
    float* ouu   = ws; ws += (size_t)BL * 128;
    float* ota   = ws; ws += (size_t)BL * 128;
    float* odu   = ws; ws += (size_t)BL * 128;
    float* puu   = ws; ws += (size_t)BL * 128;
    float* pta   = ws; ws += (size_t)BL * 128;
    float* pdu   = ws; ws += (size_t)BL * 128;
    float* yy    = ws; ws += (size_t)BL * 128;

    dim3 blk128(128), blk256(256);

    // input projections (Q for all three paths; K/V for ta/du; Kbase/Vbase for uu)
    hipLaunchKernelGGL(proj_kernel, dim3(BL), blk128, 0, stream, DUMat, 128, 128, uu_in_w, 0,   uu_in_b,       qd);
    hipLaunchKernelGGL(proj_kernel, dim3(BN), blk128, 0, stream, UUMat, 126, 126, uu_in_w, 128, uu_in_b + 128, kbase);
    hipLaunchKernelGGL(proj_kernel, dim3(BN), blk128, 0, stream, UUMat, 126, 126, uu_in_w, 256, uu_in_b + 256, vbase);
    hipLaunchKernelGGL(proj_kernel, dim3(BL), blk128, 0, stream, DUMat, 128, 128, ta_in_w, 0,   ta_in_b,       qta);
    hipLaunchKernelGGL(proj_kernel, dim3(BL), blk128, 0, stream, TAMat, 128, 128, ta_in_w, 128, ta_in_b + 128, kta);
    hipLaunchKernelGGL(proj_kernel, dim3(BL), blk128, 0, stream, TAMat, 128, 128, ta_in_w, 256, ta_in_b + 256, vta);
    hipLaunchKernelGGL(proj_kernel, dim3(BL), blk128, 0, stream, DUMat, 128, 128, du_in_w, 0,   du_in_b,       qdu);
    hipLaunchKernelGGL(proj_kernel, dim3(BL), blk128, 0, stream, DUMat, 128, 128, du_in_w, 128, du_in_b + 128, kdu);
    hipLaunchKernelGGL(proj_kernel, dim3(BL), blk128, 0, stream, DUMat, 128, 128, du_in_w, 256, du_in_b + 256, vdu);

    // attention cores
    hipLaunchKernelGGL(attn256_kernel, dim3(BL), blk256, 0, stream, qta, kta, vta, ota);
    hipLaunchKernelGGL(attn256_kernel, dim3(BL), blk256, 0, stream, qdu, kdu, vdu, odu);
    hipLaunchKernelGGL(attn_uu_kernel, dim3(BL), blk256, 0, stream, qd, kbase, vbase, CIMat, uu_in_w, ouu);

    // output projections
    hipLaunchKernelGGL(proj_kernel, dim3(BL), blk128, 0, stream, ouu, 128, 128, uu_out_w, 0, uu_out_b, puu);
    hipLaunchKernelGGL(proj_kernel, dim3(BL), blk128, 0, stream, ota, 128, 128, ta_out_w, 0, ta_out_b, pta);
    hipLaunchKernelGGL(proj_kernel, dim3(BL), blk128, 0, stream, odu, 128, 128, du_out_w, 0, du_out_b, pdu);

    // concat -> dim projection
    hipLaunchKernelGGL(dimproj_kernel, dim3(BL), blk128, 0, stream, puu, pta, pdu, dim_w, dim_b, yy);

    // batchnorm (batch stats) + relu
    hipLaunchKernelGGL(bn_kernel, dim3(128), blk256, 0, stream, yy, bn_g, bn_b, out);
}

// Round 3
// 339.051 us; speedup vs baseline: 1.2583x; 1.2583x over previous
//
#include <hip/hip_runtime.h>

// Problem constants: B=4, L=256, E=128, H=8, D=16, NU=512, NT=256. All I/O fp32.
// Pipeline (7 dispatches):
//   1. transpose_ci   : CIMat [4,512,512] -> cit (per-b transpose) so attn_uu reads rows
//   2. proj_fused     : all 9 input projections, 8-row blocking (weights reused 8x)
//   3. combine_kernel : Cxx = dim_w_slice @ xx_out_w  (folds out-proj into dim-proj)
//   4. attn256_pair   : ta2du + du2du attention cores (grid.y = 2)
//   5. attn_uu        : UU2DU attention w/ rank-2 ci correction (reads cit rows)
//   6. epilogue       : y = Cuu@ouu + Cta@ota + Cdu@odu + bias_comb
//   7. bn_kernel      : training-mode BatchNorm over (B,L) + ReLU

// ---------------- 1. CIMat transpose (coalesced both ways) ----------------
__global__ void transpose_ci(const float* __restrict__ CIMat, float* __restrict__ cit)
{
    __shared__ float tile[32][33];
    int b = blockIdx.z;
    int n0 = blockIdx.x * 32;   // source row block (n)
    int c0 = blockIdx.y * 32;   // source col block (c)
    int tx = threadIdx.x;       // 32
    int ty = threadIdx.y;       // 8
    const float* src = CIMat + (size_t)b * 512 * 512;
    float* dst = cit + (size_t)b * 512 * 512;
    for (int i = ty; i < 32; i += 8)
        tile[i][tx] = src[(size_t)(n0 + i) * 512 + c0 + tx];
    __syncthreads();
    for (int i = ty; i < 32; i += 8)
        dst[(size_t)(c0 + i) * 512 + n0 + tx] = tile[tx][i];
}

// ---------------- 2. fused input projections ----------------
// 9 tasks: 0 qd, 1 qta, 2 kta, 3 vta, 4 qdu, 5 kdu, 6 vdu (M=1024), 7 kbase, 8 vbase (M=2048)
struct ProjTasks {
    const float* x[9];
    const float* W[9];    // pre-offset to the 128-row slice
    const float* bia[9];  // pre-offset
    float* out[9];
    int x_ld[9];
    int Kdim[9];
};

__global__ void proj_fused(ProjTasks T)
{
    __shared__ float xs[8 * 128];
    int bid = blockIdx.x;
    int task, mblk;
    if (bid < 7 * 128) { task = bid >> 7; mblk = bid & 127; }
    else { int r = bid - 7 * 128; task = 7 + (r >> 8); mblk = r & 255; }
    int e = threadIdx.x;          // 128 threads
    int Kdim = T.Kdim[task];
    int x_ld = T.x_ld[task];
    const float* x = T.x[task];
    int m0 = mblk * 8;
#pragma unroll
    for (int r = 0; r < 8; ++r)
        xs[r * 128 + e] = (e < Kdim) ? x[(size_t)(m0 + r) * x_ld + e] : 0.f;
    __syncthreads();
    const float* wrow = T.W[task] + (size_t)e * 128;
    float acc[8];
    float bv = T.bia[task][e];
#pragma unroll
    for (int r = 0; r < 8; ++r) acc[r] = bv;
#pragma unroll 4
    for (int k = 0; k < 128; ++k) {
        float w = wrow[k];
#pragma unroll
        for (int r = 0; r < 8; ++r) acc[r] += w * xs[r * 128 + k];
    }
    float* out = T.out[task];
#pragma unroll
    for (int r = 0; r < 8; ++r) out[(size_t)(m0 + r) * 128 + e] = acc[r];
}

// ---------------- 3. fold out-projections into dim projection ----------------
// Cuu[e,k] = sum_j dim_w[e,j]*uu_out_w[j,k]; Cta uses dim_w[e,128+j]; Cdu uses 256+j.
// bias_comb[e] = dim_b[e] + sum_j dim_w[e,j]*uu_out_b[j] + ... (ta, du slices)
__global__ void combine_kernel(const float* __restrict__ dim_w, const float* __restrict__ dim_b,
                               const float* __restrict__ uu_ow, const float* __restrict__ uu_ob,
                               const float* __restrict__ ta_ow, const float* __restrict__ ta_ob,
                               const float* __restrict__ du_ow, const float* __restrict__ du_ob,
                               float* __restrict__ Cuu, float* __restrict__ Cta,
                               float* __restrict__ Cdu, float* __restrict__ bias_comb)
{
    __shared__ float ds[384];
    __shared__ float red[128];
    int e = blockIdx.x, k = threadIdx.x;   // 128 threads
    ds[k]       = dim_w[(size_t)e * 384 + k];
    ds[128 + k] = dim_w[(size_t)e * 384 + 128 + k];
    ds[256 + k] = dim_w[(size_t)e * 384 + 256 + k];
    __syncthreads();
    float cu = 0.f, ct = 0.f, cd = 0.f;
#pragma unroll 4
    for (int j = 0; j < 128; ++j) {
        cu += ds[j]       * uu_ow[(size_t)j * 128 + k];
        ct += ds[128 + j] * ta_ow[(size_t)j * 128 + k];
        cd += ds[256 + j] * du_ow[(size_t)j * 128 + k];
    }
    Cuu[(size_t)e * 128 + k] = cu;
    Cta[(size_t)e * 128 + k] = ct;
    Cdu[(size_t)e * 128 + k] = cd;
    red[k] = ds[k] * uu_ob[k] + ds[128 + k] * ta_ob[k] + ds[256 + k] * du_ob[k];
    __syncthreads();
    for (int off = 64; off; off >>= 1) {
        if (k < off) red[k] += red[k + off];
        __syncthreads();
    }
    if (k == 0) bias_comb[e] = dim_b[e] + red[0];
}

// ---------------- 4. ta2du + du2du attention (N=256 keys) ----------------
__global__ void attn256_pair(const float* __restrict__ q0, const float* __restrict__ k0,
                             const float* __restrict__ v0, float* __restrict__ o0,
                             const float* __restrict__ q1, const float* __restrict__ k1,
                             const float* __restrict__ v1, float* __restrict__ o1)
{
    const float* q    = blockIdx.y ? q1 : q0;
    const float* kbuf = blockIdx.y ? k1 : k0;
    const float* vbuf = blockIdx.y ? v1 : v0;
    float* o          = blockIdx.y ? o1 : o0;
    int bl = blockIdx.x;          // b*L + l, L=256
    int b  = bl >> 8;
    int tid = threadIdx.x;
    __shared__ float qs[128];
    __shared__ float sc[8 * 256];
    __shared__ float hden[8];
    if (tid < 128) qs[tid] = q[(size_t)bl * 128 + tid];
    __syncthreads();

    {
        int n = tid;
        const float* krow = kbuf + ((size_t)b * 256 + n) * 128;
#pragma unroll
        for (int h = 0; h < 8; ++h) {
            float acc = 0.f;
#pragma unroll
            for (int d = 0; d < 16; ++d) acc += qs[h * 16 + d] * krow[h * 16 + d];
            sc[h * 256 + n] = acc * 0.25f;   // 1/sqrt(16)
        }
    }
    __syncthreads();

    int h = tid >> 5, j = tid & 31;
    float mx = -1e30f;
    for (int n = j; n < 256; n += 32) mx = fmaxf(mx, sc[h * 256 + n]);
    for (int off = 16; off; off >>= 1) mx = fmaxf(mx, __shfl_down(mx, off, 32));
    mx = __shfl(mx, 0, 32);
    float p = 0.f;
    for (int n = j; n < 256; n += 32) {
        float ev = __expf(sc[h * 256 + n] - mx);
        sc[h * 256 + n] = ev;
        p += ev;
    }
    for (int off = 16; off; off >>= 1) p += __shfl_down(p, off, 32);
    if (j == 0) hden[h] = p;
    __syncthreads();

    int pr = tid >> 1, half = tid & 1;
    int hh = pr >> 4;
    const float* vcol = vbuf + (size_t)b * 256 * 128 + pr;
    float acc = 0.f;
    for (int n = half * 128; n < half * 128 + 128; ++n)
        acc += sc[hh * 256 + n] * vcol[(size_t)n * 128];
    acc += __shfl_down(acc, 1, 64);
    if (half == 0) o[(size_t)bl * 128 + pr] = acc / hden[hh];
}

// ---------------- 5. UU2DU attention (N=512, rank-2 ci correction) ----------------
__global__ void attn_uu_kernel(const float* __restrict__ qd, const float* __restrict__ kbase,
                               const float* __restrict__ vbase, const float* __restrict__ cit,
                               const float* __restrict__ in_w, float* __restrict__ o)
{
    int bl = blockIdx.x;          // b*L + l
    int b = bl >> 8, l = bl & 255;
    int tid = threadIdx.x;
    __shared__ float qs[128];
    __shared__ float sc[8 * 512];
    __shared__ float ci0s[512], ci1s[512];
    __shared__ float qk126[8], qk127[8];
    __shared__ float hden[8], hs0[8], hs1[8];

    if (tid < 128) qs[tid] = qd[(size_t)bl * 128 + tid];
    __syncthreads();
    if (tid < 8) {
        float a = 0.f, c = 0.f;
#pragma unroll
        for (int d = 0; d < 16; ++d) {
            float qv = qs[tid * 16 + d];
            a += qv * in_w[(size_t)(128 + tid * 16 + d) * 128 + 126];
            c += qv * in_w[(size_t)(128 + tid * 16 + d) * 128 + 127];
        }
        qk126[tid] = a; qk127[tid] = c;
    }
    // contiguous rows of the transposed CI
    for (int n = tid; n < 512; n += 256) {
        ci0s[n] = cit[((size_t)b * 512 + l) * 512 + n];
        ci1s[n] = cit[((size_t)b * 512 + 256 + l) * 512 + n];
    }
    __syncthreads();

    for (int n = tid; n < 512; n += 256) {
        const float* krow = kbase + ((size_t)b * 512 + n) * 128;
        float c0 = ci0s[n], c1 = ci1s[n];
#pragma unroll
        for (int h = 0; h < 8; ++h) {
            float acc = c0 * qk126[h] + c1 * qk127[h];
#pragma unroll
            for (int d = 0; d < 16; ++d) acc += qs[h * 16 + d] * krow[h * 16 + d];
            sc[h * 512 + n] = acc * 0.25f;
        }
    }
    __syncthreads();

    int h = tid >> 5, j = tid & 31;
    float mx = -1e30f;
    for (int n = j; n < 512; n += 32) mx = fmaxf(mx, sc[h * 512 + n]);
    for (int off = 16; off; off >>= 1) mx = fmaxf(mx, __shfl_down(mx, off, 32));
    mx = __shfl(mx, 0, 32);
    float p = 0.f, s0 = 0.f, s1 = 0.f;
    for (int n = j; n < 512; n += 32) {
        float ev = __expf(sc[h * 512 + n] - mx);
        sc[h * 512 + n] = ev;
        p += ev; s0 += ev * ci0s[n]; s1 += ev * ci1s[n];
    }
    for (int off = 16; off; off >>= 1) {
        p  += __shfl_down(p, off, 32);
        s0 += __shfl_down(s0, off, 32);
        s1 += __shfl_down(s1, off, 32);
    }
    if (j == 0) { hden[h] = p; hs0[h] = s0; hs1[h] = s1; }
    __syncthreads();

    int pr = tid >> 1, half = tid & 1;
    int hh = pr >> 4;
    const float* vcol = vbase + (size_t)b * 512 * 128 + pr;
    float acc = 0.f;
    for (int n = half * 256; n < half * 256 + 256; ++n)
        acc += sc[hh * 512 + n] * vcol[(size_t)n * 128];
    acc += __shfl_down(acc, 1, 64);
    if (half == 0) {
        float wv126 = in_w[(size_t)(256 + pr) * 128 + 126];
        float wv127 = in_w[(size_t)(256 + pr) * 128 + 127];
        o[(size_t)bl * 128 + pr] = (acc + hs0[hh] * wv126 + hs1[hh] * wv127) / hden[hh];
    }
}

// ---------------- 6. epilogue: y = Cuu@ouu + Cta@ota + Cdu@odu + bias_comb ----------------
__global__ void epilogue_kernel(const float* __restrict__ ouu, const float* __restrict__ ota,
                                const float* __restrict__ odu,
                                const float* __restrict__ Cuu, const float* __restrict__ Cta,
                                const float* __restrict__ Cdu, const float* __restrict__ bias_comb,
                                float* __restrict__ y)
{
    __shared__ float xs[8 * 384];
    int m0 = blockIdx.x * 8;
    int e = threadIdx.x;   // 128
#pragma unroll
    for (int r = 0; r < 8; ++r) {
        xs[r * 384 + e]       = ouu[(size_t)(m0 + r) * 128 + e];
        xs[r * 384 + 128 + e] = ota[(size_t)(m0 + r) * 128 + e];
        xs[r * 384 + 256 + e] = odu[(size_t)(m0 + r) * 128 + e];
    }
    __syncthreads();
    float acc[8];
    float bc = bias_comb[e];
#pragma unroll
    for (int r = 0; r < 8; ++r) acc[r] = bc;
    const float* cu = Cuu + (size_t)e * 128;
    const float* ct = Cta + (size_t)e * 128;
    const float* cd = Cdu + (size_t)e * 128;
#pragma unroll 2
    for (int k = 0; k < 128; ++k) {
        float a = cu[k], bb = ct[k], c = cd[k];
#pragma unroll
        for (int r = 0; r < 8; ++r)
            acc[r] += a * xs[r * 384 + k] + bb * xs[r * 384 + 128 + k] + c * xs[r * 384 + 256 + k];
    }
#pragma unroll
    for (int r = 0; r < 8; ++r) y[(size_t)(m0 + r) * 128 + e] = acc[r];
}

// ---------------- 7. BatchNorm (batch stats over B*L=1024) + ReLU ----------------
__global__ void bn_kernel(const float* __restrict__ y, const float* __restrict__ gamma,
                          const float* __restrict__ beta, float* __restrict__ out)
{
    int e = blockIdx.x;     // channel
    int tid = threadIdx.x;  // 256
    __shared__ float red[256], red2[256];
    float s = 0.f, s2 = 0.f;
    for (int m = tid; m < 1024; m += 256) {
        float v = y[(size_t)m * 128 + e];
        s += v; s2 += v * v;
    }
    red[tid] = s; red2[tid] = s2;
    __syncthreads();
    for (int off = 128; off; off >>= 1) {
        if (tid < off) { red[tid] += red[tid + off]; red2[tid] += red2[tid + off]; }
        __syncthreads();
    }
    float mean = red[0] * (1.f / 1024.f);
    float var  = red2[0] * (1.f / 1024.f) - mean * mean;
    float inv  = rsqrtf(var + 1e-5f);
    float g = gamma[e], bt = beta[e];
    for (int m = tid; m < 1024; m += 256) {
        float v = (y[(size_t)m * 128 + e] - mean) * inv * g + bt;
        out[(size_t)m * 128 + e] = fmaxf(v, 0.f);
    }
}

extern "C" void kernel_launch(void* const* d_in, const int* in_sizes, int n_in,
                              void* d_out, int out_size, void* d_ws, size_t ws_size,
                              hipStream_t stream)
{
    (void)in_sizes; (void)n_in; (void)out_size; (void)ws_size;
    const float* UUMat    = (const float*)d_in[0];   // [4,512,126]
    const float* DUMat    = (const float*)d_in[1];   // [4,256,128]
    const float* TAMat    = (const float*)d_in[2];   // [4,256,128]
    const float* CIMat    = (const float*)d_in[3];   // [4,512,512]
    const float* uu_in_w  = (const float*)d_in[4];   // [384,128]
    const float* uu_in_b  = (const float*)d_in[5];
    const float* uu_out_w = (const float*)d_in[6];   // [128,128]
    const float* uu_out_b = (const float*)d_in[7];
    const float* ta_in_w  = (const float*)d_in[8];
    const float* ta_in_b  = (const float*)d_in[9];
    const float* ta_out_w = (const float*)d_in[10];
    const float* ta_out_b = (const float*)d_in[11];
    const float* du_in_w  = (const float*)d_in[12];
    const float* du_in_b  = (const float*)d_in[13];
    const float* du_out_w = (const float*)d_in[14];
    const float* du_out_b = (const float*)d_in[15];
    const float* dim_w    = (const float*)d_in[16];  // [128,384]
    const float* dim_b    = (const float*)d_in[17];
    const float* bn_g     = (const float*)d_in[18];
    const float* bn_b     = (const float*)d_in[19];
    float* out = (float*)d_out;

    const int BL = 4 * 256;   // 1024 query rows
    const int BN = 4 * 512;   // 2048 UU rows
    float* ws = (float*)d_ws;
    float* cit   = ws; ws += (size_t)4 * 512 * 512;
    float* qd    = ws; ws += (size_t)BL * 128;
    float* kbase = ws; ws += (size_t)BN * 128;
    float* vbase = ws; ws += (size_t)BN * 128;
    float* qta   = ws; ws += (size_t)BL * 128;
    float* kta   = ws; ws += (size_t)BL * 128;
    float* vta   = ws; ws += (size_t)BL * 128;
    float* qdu   = ws; ws += (size_t)BL * 128;
    float* kdu   = ws; ws += (size_t)BL * 128;
    float* vdu   = ws; ws += (size_t)BL * 128;
    float* ouu   = ws; ws += (size_t)BL * 128;
    float* ota   = ws; ws += (size_t)BL * 128;
    float* odu   = ws; ws += (size_t)BL * 128;
    float* yy    = ws; ws += (size_t)BL * 128;
    float* Cuu   = ws; ws += 128 * 128;
    float* Cta   = ws; ws += 128 * 128;
    float* Cdu   = ws; ws += 128 * 128;
    float* bcomb = ws; ws += 128;

    // 1. transpose CI
    hipLaunchKernelGGL(transpose_ci, dim3(16, 16, 4), dim3(32, 8), 0, stream, CIMat, cit);

    // 2. all input projections
    ProjTasks T;
    T.x[0] = DUMat; T.W[0] = uu_in_w;             T.bia[0] = uu_in_b;       T.out[0] = qd;    T.x_ld[0] = 128; T.Kdim[0] = 128;
    T.x[1] = DUMat; T.W[1] = ta_in_w;             T.bia[1] = ta_in_b;       T.out[1] = qta;   T.x_ld[1] = 128; T.Kdim[1] = 128;
    T.x[2] = TAMat; T.W[2] = ta_in_w + 128 * 128; T.bia[2] = ta_in_b + 128; T.out[2] = kta;   T.x_ld[2] = 128; T.Kdim[2] = 128;
    T.x[3] = TAMat; T.W[3] = ta_in_w + 256 * 128; T.bia[3] = ta_in_b + 256; T.out[3] = vta;   T.x_ld[3] = 128; T.Kdim[3] = 128;
    T.x[4] = DUMat; T.W[4] = du_in_w;             T.bia[4] = du_in_b;       T.out[4] = qdu;   T.x_ld[4] = 128; T.Kdim[4] = 128;
    T.x[5] = DUMat; T.W[5] = du_in_w + 128 * 128; T.bia[5] = du_in_b + 128; T.out[5] = kdu;   T.x_ld[5] = 128; T.Kdim[5] = 128;
    T.x[6] = DUMat; T.W[6] = du_in_w + 256 * 128; T.bia[6] = du_in_b + 256; T.out[6] = vdu;   T.x_ld[6] = 128; T.Kdim[6] = 128;
    T.x[7] = UUMat; T.W[7] = uu_in_w + 128 * 128; T.bia[7] = uu_in_b + 128; T.out[7] = kbase; T.x_ld[7] = 126; T.Kdim[7] = 126;
    T.x[8] = UUMat; T.W[8] = uu_in_w + 256 * 128; T.bia[8] = uu_in_b + 256; T.out[8] = vbase; T.x_ld[8] = 126; T.Kdim[8] = 126;
    hipLaunchKernelGGL(proj_fused, dim3(7 * 128 + 2 * 256), dim3(128), 0, stream, T);

    // 3. fold out-projections into dim projection
    hipLaunchKernelGGL(combine_kernel, dim3(128), dim3(128), 0, stream,
                       dim_w, dim_b, uu_out_w, uu_out_b, ta_out_w, ta_out_b,
                       du_out_w, du_out_b, Cuu, Cta, Cdu, bcomb);

    // 4. ta2du + du2du attention
    hipLaunchKernelGGL(attn256_pair, dim3(BL, 2), dim3(256), 0, stream,
                       qta, kta, vta, ota, qdu, kdu, vdu, odu);

    // 5. UU2DU attention
    hipLaunchKernelGGL(attn_uu_kernel, dim3(BL), dim3(256), 0, stream,
                       qd, kbase, vbase, cit, uu_in_w, ouu);

    // 6. epilogue
    hipLaunchKernelGGL(epilogue_kernel, dim3(BL / 8), dim3(128), 0, stream,
                       ouu, ota, odu, Cuu, Cta, Cdu, bcomb, yy);

    // 7. batchnorm + relu
    hipLaunchKernelGGL(bn_kernel, dim3(128), dim3(256), 0, stream, yy, bn_g, bn_b, out);
}

// Round 4
// 224.348 us; speedup vs baseline: 1.9017x; 1.5113x over previous
//
#include <hip/hip_runtime.h>

// B=4, L=256, E=128, H=8, D=16, NU=512, NT=256. All I/O fp32.
// 5 dispatches:
//   1. pre_fused    : CI transpose + 9 input projections + out/dim-proj fold
//   2. attn256_pair : ta2du + du2du attention (4 query rows per block)
//   3. attn_uu      : UU2DU attention, rank-2 ci correction (2 query rows per block)
//   4. epilogue     : y = Cuu@ouu + Cta@ota + Cdu@odu + bias_comb
//   5. bn_kernel    : training-mode BatchNorm over (B,L) + ReLU

struct PreArgs {
    const float* x[9]; const float* W[9]; const float* bia[9]; float* out[9];
    int Kdim[9];
    const float* CIMat; float* cit;
    const float* dim_w; const float* dim_b;
    const float* uu_ow; const float* uu_ob;
    const float* ta_ow; const float* ta_ob;
    const float* du_ow; const float* du_ob;
    float* Cuu; float* Cta; float* Cdu; float* bias_comb;
};

#define PROJ_BLOCKS  (7 * 128 + 2 * 256)   // 1408
#define TRANS_BLOCKS (4 * 256)             // 1024
#define COMB_BLOCKS  128

__global__ __launch_bounds__(128) void pre_fused(PreArgs A)
{
    __shared__ __align__(16) float smem[1056];
    int bid = blockIdx.x;
    int tid = threadIdx.x;

    if (bid < PROJ_BLOCKS) {
        // ---- projection: out[m,e] = sum_k x[m,k] * W[e,k] + bias[e], 8 rows/block ----
        float* xs = smem;   // 8*128
        int task, mblk;
        if (bid < 7 * 128) { task = bid >> 7; mblk = bid & 127; }
        else { int r = bid - 7 * 128; task = 7 + (r >> 8); mblk = r & 255; }
        int e = tid;
        int Kdim = A.Kdim[task];
        const float* x = A.x[task];
        int m0 = mblk * 8;
        if (Kdim == 128) {
            const float4* x4 = (const float4*)(x + (size_t)m0 * 128);
            float4* xs4 = (float4*)xs;
            xs4[e] = x4[e];
            xs4[e + 128] = x4[e + 128];
        } else {
#pragma unroll
            for (int r = 0; r < 8; ++r)
                xs[r * 128 + e] = (e < Kdim) ? x[(size_t)(m0 + r) * Kdim + e] : 0.f;
        }
        __syncthreads();
        const float4* w4 = (const float4*)(A.W[task] + (size_t)e * 128);
        const float4* xs4 = (const float4*)xs;
        float acc[8];
        float bv = A.bia[task][e];
#pragma unroll
        for (int r = 0; r < 8; ++r) acc[r] = bv;
#pragma unroll 8
        for (int c = 0; c < 32; ++c) {
            float4 w = w4[c];
#pragma unroll
            for (int r = 0; r < 8; ++r) {
                float4 xv = xs4[r * 32 + c];
                acc[r] += w.x * xv.x + w.y * xv.y + w.z * xv.z + w.w * xv.w;
            }
        }
        float* out = A.out[task];
#pragma unroll
        for (int r = 0; r < 8; ++r) out[(size_t)(m0 + r) * 128 + e] = acc[r];

    } else if (bid < PROJ_BLOCKS + TRANS_BLOCKS) {
        // ---- CI transpose: cit[b][c][n] = CIMat[b][n][c], 32x32 tiles ----
        int tb = bid - PROJ_BLOCKS;
        int b = tb >> 8;
        int t = tb & 255;
        int n0 = (t >> 4) * 32, c0 = (t & 15) * 32;
        float (*tile)[33] = (float(*)[33])smem;
        int tx = tid & 31, ty = tid >> 5;   // 32 x 4
        const float* src = A.CIMat + (size_t)b * 262144;
        float* dst = A.cit + (size_t)b * 262144;
#pragma unroll
        for (int i = ty; i < 32; i += 4)
            tile[i][tx] = src[(size_t)(n0 + i) * 512 + c0 + tx];
        __syncthreads();
#pragma unroll
        for (int i = ty; i < 32; i += 4)
            dst[(size_t)(c0 + i) * 512 + n0 + tx] = tile[tx][i];

    } else {
        // ---- fold out-projections into dim projection ----
        float* ds = smem;          // 384
        float* red = smem + 384;   // 128
        int e = bid - PROJ_BLOCKS - TRANS_BLOCKS;
        int k = tid;
        ds[k]       = A.dim_w[(size_t)e * 384 + k];
        ds[128 + k] = A.dim_w[(size_t)e * 384 + 128 + k];
        ds[256 + k] = A.dim_w[(size_t)e * 384 + 256 + k];
        __syncthreads();
        float cu = 0.f, ct = 0.f, cd = 0.f;
#pragma unroll 4
        for (int j = 0; j < 128; ++j) {
            cu += ds[j]       * A.uu_ow[(size_t)j * 128 + k];
            ct += ds[128 + j] * A.ta_ow[(size_t)j * 128 + k];
            cd += ds[256 + j] * A.du_ow[(size_t)j * 128 + k];
        }
        A.Cuu[(size_t)e * 128 + k] = cu;
        A.Cta[(size_t)e * 128 + k] = ct;
        A.Cdu[(size_t)e * 128 + k] = cd;
        red[k] = ds[k] * A.uu_ob[k] + ds[128 + k] * A.ta_ob[k] + ds[256 + k] * A.du_ob[k];
        __syncthreads();
        for (int off = 64; off; off >>= 1) {
            if (k < off) red[k] += red[k + off];
            __syncthreads();
        }
        if (k == 0) A.bias_comb[e] = A.dim_b[e] + red[0];
    }
}

// ---------------- attn256: 4 query rows per block, N=256 keys ----------------
__global__ __launch_bounds__(256) void attn256_pair(
    const float* __restrict__ q0, const float* __restrict__ k0,
    const float* __restrict__ v0, float* __restrict__ o0,
    const float* __restrict__ q1, const float* __restrict__ k1,
    const float* __restrict__ v1, float* __restrict__ o1)
{
    const float* q    = blockIdx.y ? q1 : q0;
    const float* kbuf = blockIdx.y ? k1 : k0;
    const float* vbuf = blockIdx.y ? v1 : v0;
    float* o          = blockIdx.y ? o1 : o0;
    int b  = blockIdx.x >> 6;
    int l0 = (blockIdx.x & 63) * 4;
    int bl0 = b * 256 + l0;
    int tid = threadIdx.x;

    __shared__ __align__(16) float qs[4 * 128];
    __shared__ __align__(16) float sc[8 * 256 * 4];   // [h][n][l]
    __shared__ float hden[32];                        // [l*8+h]

    if (tid < 128) ((float4*)qs)[tid] = ((const float4*)(q + (size_t)bl0 * 128))[tid];
    __syncthreads();

    // ---- scores: thread = key n ----
    {
        int n = tid;
        const float4* krow = (const float4*)(kbuf + ((size_t)b * 256 + n) * 128);
        const float4* qs4 = (const float4*)qs;
        float acc[4][8];
#pragma unroll
        for (int l = 0; l < 4; ++l)
#pragma unroll
            for (int h = 0; h < 8; ++h) acc[l][h] = 0.f;
#pragma unroll 8
        for (int c = 0; c < 32; ++c) {
            float4 kv = krow[c];
            int h = c >> 2;
#pragma unroll
            for (int l = 0; l < 4; ++l) {
                float4 qv = qs4[l * 32 + c];
                acc[l][h] += kv.x * qv.x + kv.y * qv.y + kv.z * qv.z + kv.w * qv.w;
            }
        }
        float4* sc4 = (float4*)sc;
#pragma unroll
        for (int h = 0; h < 8; ++h) {
            float4 v;
            v.x = acc[0][h] * 0.25f; v.y = acc[1][h] * 0.25f;
            v.z = acc[2][h] * 0.25f; v.w = acc[3][h] * 0.25f;
            sc4[h * 256 + n] = v;
        }
    }
    __syncthreads();

    // ---- softmax: 8 head-groups x 32 lanes, all 4 l as float4 ----
    {
        int h = tid >> 5, j = tid & 31;
        float4* row = (float4*)sc + h * 256;
        float4 mx = { -1e30f, -1e30f, -1e30f, -1e30f };
        for (int n = j; n < 256; n += 32) {
            float4 v = row[n];
            mx.x = fmaxf(mx.x, v.x); mx.y = fmaxf(mx.y, v.y);
            mx.z = fmaxf(mx.z, v.z); mx.w = fmaxf(mx.w, v.w);
        }
#pragma unroll
        for (int off = 16; off; off >>= 1) {
            mx.x = fmaxf(mx.x, __shfl_down(mx.x, off, 32));
            mx.y = fmaxf(mx.y, __shfl_down(mx.y, off, 32));
            mx.z = fmaxf(mx.z, __shfl_down(mx.z, off, 32));
            mx.w = fmaxf(mx.w, __shfl_down(mx.w, off, 32));
        }
        mx.x = __shfl(mx.x, 0, 32); mx.y = __shfl(mx.y, 0, 32);
        mx.z = __shfl(mx.z, 0, 32); mx.w = __shfl(mx.w, 0, 32);
        float4 s = { 0.f, 0.f, 0.f, 0.f };
        for (int n = j; n < 256; n += 32) {
            float4 v = row[n];
            v.x = __expf(v.x - mx.x); v.y = __expf(v.y - mx.y);
            v.z = __expf(v.z - mx.z); v.w = __expf(v.w - mx.w);
            row[n] = v;
            s.x += v.x; s.y += v.y; s.z += v.z; s.w += v.w;
        }
#pragma unroll
        for (int off = 16; off; off >>= 1) {
            s.x += __shfl_down(s.x, off, 32); s.y += __shfl_down(s.y, off, 32);
            s.z += __shfl_down(s.z, off, 32); s.w += __shfl_down(s.w, off, 32);
        }
        if (j == 0) {
            hden[h] = s.x; hden[8 + h] = s.y; hden[16 + h] = s.z; hden[24 + h] = s.w;
        }
    }
    __syncthreads();

    // ---- V pass: pair of threads per output column ----
    {
        int pr = tid >> 1, half = tid & 1;
        int hh = pr >> 4;
        const float* vcol = vbuf + (size_t)b * 256 * 128 + pr;
        const float4* sc4 = (const float4*)sc + hh * 256;
        float acc[4] = { 0.f, 0.f, 0.f, 0.f };
        int n0 = half * 128;
#pragma unroll 8
        for (int n = n0; n < n0 + 128; ++n) {
            float vv = vcol[(size_t)n * 128];
            float4 p = sc4[n];
            acc[0] += p.x * vv; acc[1] += p.y * vv; acc[2] += p.z * vv; acc[3] += p.w * vv;
        }
#pragma unroll
        for (int l = 0; l < 4; ++l) {
            float r = acc[l] + __shfl_down(acc[l], 1, 64);
            if (half == 0) o[(size_t)(bl0 + l) * 128 + pr] = r / hden[l * 8 + hh];
        }
    }
}

// ---------------- attn_uu: 2 query rows per block, N=512 keys ----------------
__global__ __launch_bounds__(256) void attn_uu_kernel(
    const float* __restrict__ qd, const float* __restrict__ kbase,
    const float* __restrict__ vbase, const float* __restrict__ cit,
    const float* __restrict__ in_w, float* __restrict__ o)
{
    int b  = blockIdx.x >> 7;
    int l0 = (blockIdx.x & 127) * 2;
    int bl0 = b * 256 + l0;
    int tid = threadIdx.x;

    __shared__ __align__(16) float qs[2 * 128];
    __shared__ __align__(16) float sc[8 * 512 * 2];   // [h][n][l]
    __shared__ __align__(16) float ci0s[2 * 512];     // [l][n]
    __shared__ __align__(16) float ci1s[2 * 512];
    __shared__ float qk126[16], qk127[16];            // [l*8+h]
    __shared__ float hden[16], hs0[16], hs1[16];

    if (tid < 64) ((float4*)qs)[tid] = ((const float4*)(qd + (size_t)bl0 * 128))[tid];
    if (tid < 128) {
        // 4 source rows of cit, each 512 floats = 128 float4
        const float4* r00 = (const float4*)(cit + ((size_t)b * 512 + l0) * 512);
        const float4* r01 = (const float4*)(cit + ((size_t)b * 512 + l0 + 1) * 512);
        const float4* r10 = (const float4*)(cit + ((size_t)b * 512 + 256 + l0) * 512);
        const float4* r11 = (const float4*)(cit + ((size_t)b * 512 + 256 + l0 + 1) * 512);
        ((float4*)ci0s)[tid]       = r00[tid];
        ((float4*)ci0s)[128 + tid] = r01[tid];
        ((float4*)ci1s)[tid]       = r10[tid];
        ((float4*)ci1s)[128 + tid] = r11[tid];
    }
    __syncthreads();
    if (tid < 16) {
        int l = tid >> 3, h = tid & 7;
        float a = 0.f, c = 0.f;
#pragma unroll
        for (int d = 0; d < 16; ++d) {
            float qv = qs[l * 128 + h * 16 + d];
            a += qv * in_w[(size_t)(128 + h * 16 + d) * 128 + 126];
            c += qv * in_w[(size_t)(128 + h * 16 + d) * 128 + 127];
        }
        qk126[tid] = a; qk127[tid] = c;
    }
    __syncthreads();

    // ---- scores: thread handles n = tid and tid+256 ----
    const float4* qs4 = (const float4*)qs;
#pragma unroll
    for (int nn = 0; nn < 2; ++nn) {
        int n = tid + nn * 256;
        const float4* krow = (const float4*)(kbase + ((size_t)b * 512 + n) * 128);
        float acc[2][8];
#pragma unroll
        for (int l = 0; l < 2; ++l)
#pragma unroll
            for (int h = 0; h < 8; ++h) acc[l][h] = 0.f;
#pragma unroll 8
        for (int c = 0; c < 32; ++c) {
            float4 kv = krow[c];
            int h = c >> 2;
#pragma unroll
            for (int l = 0; l < 2; ++l) {
                float4 qv = qs4[l * 32 + c];
                acc[l][h] += kv.x * qv.x + kv.y * qv.y + kv.z * qv.z + kv.w * qv.w;
            }
        }
        float c00 = ci0s[n], c01 = ci0s[512 + n];
        float c10 = ci1s[n], c11 = ci1s[512 + n];
        float2* sc2 = (float2*)sc;
#pragma unroll
        for (int h = 0; h < 8; ++h) {
            float2 v;
            v.x = (acc[0][h] + c00 * qk126[h]     + c10 * qk127[h])     * 0.25f;
            v.y = (acc[1][h] + c01 * qk126[8 + h] + c11 * qk127[8 + h]) * 0.25f;
            sc2[h * 512 + n] = v;
        }
    }
    __syncthreads();

    // ---- softmax + ci-weighted sums: 8 head-groups x 32 lanes ----
    {
        int h = tid >> 5, j = tid & 31;
        float2* row = (float2*)sc + h * 512;
        float2 mx = { -1e30f, -1e30f };
        for (int n = j; n < 512; n += 32) {
            float2 v = row[n];
            mx.x = fmaxf(mx.x, v.x); mx.y = fmaxf(mx.y, v.y);
        }
#pragma unroll
        for (int off = 16; off; off >>= 1) {
            mx.x = fmaxf(mx.x, __shfl_down(mx.x, off, 32));
            mx.y = fmaxf(mx.y, __shfl_down(mx.y, off, 32));
        }
        mx.x = __shfl(mx.x, 0, 32); mx.y = __shfl(mx.y, 0, 32);
        float2 s = { 0.f, 0.f }, s0 = { 0.f, 0.f }, s1 = { 0.f, 0.f };
        for (int n = j; n < 512; n += 32) {
            float2 v = row[n];
            v.x = __expf(v.x - mx.x); v.y = __expf(v.y - mx.y);
            row[n] = v;
            s.x += v.x; s.y += v.y;
            s0.x += v.x * ci0s[n]; s0.y += v.y * ci0s[512 + n];
            s1.x += v.x * ci1s[n]; s1.y += v.y * ci1s[512 + n];
        }
#pragma unroll
        for (int off = 16; off; off >>= 1) {
            s.x  += __shfl_down(s.x, off, 32);  s.y  += __shfl_down(s.y, off, 32);
            s0.x += __shfl_down(s0.x, off, 32); s0.y += __shfl_down(s0.y, off, 32);
            s1.x += __shfl_down(s1.x, off, 32); s1.y += __shfl_down(s1.y, off, 32);
        }
        if (j == 0) {
            hden[h] = s.x;  hden[8 + h] = s.y;
            hs0[h]  = s0.x; hs0[8 + h]  = s0.y;
            hs1[h]  = s1.x; hs1[8 + h]  = s1.y;
        }
    }
    __syncthreads();

    // ---- V pass ----
    {
        int pr = tid >> 1, half = tid & 1;
        int hh = pr >> 4;
        const float* vcol = vbase + (size_t)b * 512 * 128 + pr;
        const float2* sc2 = (const float2*)sc + hh * 512;
        float acc[2] = { 0.f, 0.f };
        int n0 = half * 256;
#pragma unroll 8
        for (int n = n0; n < n0 + 256; ++n) {
            float vv = vcol[(size_t)n * 128];
            float2 p = sc2[n];
            acc[0] += p.x * vv; acc[1] += p.y * vv;
        }
        float wv126 = in_w[(size_t)(256 + pr) * 128 + 126];
        float wv127 = in_w[(size_t)(256 + pr) * 128 + 127];
#pragma unroll
        for (int l = 0; l < 2; ++l) {
            float r = acc[l] + __shfl_down(acc[l], 1, 64);
            if (half == 0)
                o[(size_t)(bl0 + l) * 128 + pr] =
                    (r + hs0[l * 8 + hh] * wv126 + hs1[l * 8 + hh] * wv127) / hden[l * 8 + hh];
        }
    }
}

// ---------------- epilogue: y = Cuu@ouu + Cta@ota + Cdu@odu + bias_comb ----------------
__global__ __launch_bounds__(128) void epilogue_kernel(
    const float* __restrict__ ouu, const float* __restrict__ ota,
    const float* __restrict__ odu,
    const float* __restrict__ Cuu, const float* __restrict__ Cta,
    const float* __restrict__ Cdu, const float* __restrict__ bias_comb,
    float* __restrict__ y)
{
    __shared__ __align__(16) float xs[8 * 384];
    int m0 = blockIdx.x * 8;
    int e = threadIdx.x;   // 128
#pragma unroll
    for (int r = 0; r < 8; ++r) {
        xs[r * 384 + e]       = ouu[(size_t)(m0 + r) * 128 + e];
        xs[r * 384 + 128 + e] = ota[(size_t)(m0 + r) * 128 + e];
        xs[r * 384 + 256 + e] = odu[(size_t)(m0 + r) * 128 + e];
    }
    __syncthreads();
    const float4* cu4 = (const float4*)(Cuu + (size_t)e * 128);
    const float4* ct4 = (const float4*)(Cta + (size_t)e * 128);
    const float4* cd4 = (const float4*)(Cdu + (size_t)e * 128);
    const float4* xs4 = (const float4*)xs;   // row pitch 96 float4
    float acc[8];
    float bc = bias_comb[e];
#pragma unroll
    for (int r = 0; r < 8; ++r) acc[r] = bc;
#pragma unroll 4
    for (int c = 0; c < 32; ++c) {
        float4 a = cu4[c], bb = ct4[c], d = cd4[c];
#pragma unroll
        for (int r = 0; r < 8; ++r) {
            float4 xu = xs4[r * 96 + c];
            float4 xt = xs4[r * 96 + 32 + c];
            float4 xd = xs4[r * 96 + 64 + c];
            acc[r] += a.x * xu.x + a.y * xu.y + a.z * xu.z + a.w * xu.w
                    + bb.x * xt.x + bb.y * xt.y + bb.z * xt.z + bb.w * xt.w
                    + d.x * xd.x + d.y * xd.y + d.z * xd.z + d.w * xd.w;
        }
    }
#pragma unroll
    for (int r = 0; r < 8; ++r) y[(size_t)(m0 + r) * 128 + e] = acc[r];
}

// ---------------- BatchNorm (batch stats over 1024 rows) + ReLU, coalesced ----------------
__global__ __launch_bounds__(256) void bn_kernel(
    const float* __restrict__ y, const float* __restrict__ gamma,
    const float* __restrict__ beta, float* __restrict__ out)
{
    __shared__ float rs[256], rs2[256], mval[16], ival[16];
    int e0 = blockIdx.x * 16;                       // 8 blocks x 16 channels
    int chi = threadIdx.x & 15, rg = threadIdx.x >> 4;
    int e = e0 + chi;
    float s = 0.f, s2 = 0.f;
    for (int m = rg; m < 1024; m += 16) {
        float v = y[(size_t)m * 128 + e];
        s += v; s2 += v * v;
    }
    rs[threadIdx.x] = s; rs2[threadIdx.x] = s2;
    __syncthreads();
    for (int off = 128; off >= 16; off >>= 1) {
        if (threadIdx.x < off) {
            rs[threadIdx.x] += rs[threadIdx.x + off];
            rs2[threadIdx.x] += rs2[threadIdx.x + off];
        }
        __syncthreads();
    }
    if (threadIdx.x < 16) {
        float mean = rs[threadIdx.x] * (1.f / 1024.f);
        float var = rs2[threadIdx.x] * (1.f / 1024.f) - mean * mean;
        mval[threadIdx.x] = mean;
        ival[threadIdx.x] = rsqrtf(var + 1e-5f);
    }
    __syncthreads();
    float mean = mval[chi], inv = ival[chi];
    float g = gamma[e], bt = beta[e];
    for (int m = rg; m < 1024; m += 16) {
        float v = (y[(size_t)m * 128 + e] - mean) * inv * g + bt;
        out[(size_t)m * 128 + e] = fmaxf(v, 0.f);
    }
}

extern "C" void kernel_launch(void* const* d_in, const int* in_sizes, int n_in,
                              void* d_out, int out_size, void* d_ws, size_t ws_size,
                              hipStream_t stream)
{
    (void)in_sizes; (void)n_in; (void)out_size; (void)ws_size;
    const float* UUMat    = (const float*)d_in[0];
    const float* DUMat    = (const float*)d_in[1];
    const float* TAMat    = (const float*)d_in[2];
    const float* CIMat    = (const float*)d_in[3];
    const float* uu_in_w  = (const float*)d_in[4];
    const float* uu_in_b  = (const float*)d_in[5];
    const float* uu_out_w = (const float*)d_in[6];
    const float* uu_out_b = (const float*)d_in[7];
    const float* ta_in_w  = (const float*)d_in[8];
    const float* ta_in_b  = (const float*)d_in[9];
    const float* ta_out_w = (const float*)d_in[10];
    const float* ta_out_b = (const float*)d_in[11];
    const float* du_in_w  = (const float*)d_in[12];
    const float* du_in_b  = (const float*)d_in[13];
    const float* du_out_w = (const float*)d_in[14];
    const float* du_out_b = (const float*)d_in[15];
    const float* dim_w    = (const float*)d_in[16];
    const float* dim_b    = (const float*)d_in[17];
    const float* bn_g     = (const float*)d_in[18];
    const float* bn_b     = (const float*)d_in[19];
    float* out = (float*)d_out;

    const int BL = 4 * 256;
    const int BN = 4 * 512;
    float* ws = (float*)d_ws;
    float* cit   = ws; ws += (size_t)4 * 512 * 512;
    float* qd    = ws; ws += (size_t)BL * 128;
    float* kbase = ws; ws += (size_t)BN * 128;
    float* vbase = ws; ws += (size_t)BN * 128;
    float* qta   = ws; ws += (size_t)BL * 128;
    float* kta   = ws; ws += (size_t)BL * 128;
    float* vta   = ws; ws += (size_t)BL * 128;
    float* qdu   = ws; ws += (size_t)BL * 128;
    float* kdu   = ws; ws += (size_t)BL * 128;
    float* vdu   = ws; ws += (size_t)BL * 128;
    float* ouu   = ws; ws += (size_t)BL * 128;
    float* ota   = ws; ws += (size_t)BL * 128;
    float* odu   = ws; ws += (size_t)BL * 128;
    float* yy    = ws; ws += (size_t)BL * 128;
    float* Cuu   = ws; ws += 128 * 128;
    float* Cta   = ws; ws += 128 * 128;
    float* Cdu   = ws; ws += 128 * 128;
    float* bcomb = ws; ws += 128;

    PreArgs A;
    A.x[0] = DUMat; A.W[0] = uu_in_w;             A.bia[0] = uu_in_b;       A.out[0] = qd;    A.Kdim[0] = 128;
    A.x[1] = DUMat; A.W[1] = ta_in_w;             A.bia[1] = ta_in_b;       A.out[1] = qta;   A.Kdim[1] = 128;
    A.x[2] = TAMat; A.W[2] = ta_in_w + 128 * 128; A.bia[2] = ta_in_b + 128; A.out[2] = kta;   A.Kdim[2] = 128;
    A.x[3] = TAMat; A.W[3] = ta_in_w + 256 * 128; A.bia[3] = ta_in_b + 256; A.out[3] = vta;   A.Kdim[3] = 128;
    A.x[4] = DUMat; A.W[4] = du_in_w;             A.bia[4] = du_in_b;       A.out[4] = qdu;   A.Kdim[4] = 128;
    A.x[5] = DUMat; A.W[5] = du_in_w + 128 * 128; A.bia[5] = du_in_b + 128; A.out[5] = kdu;   A.Kdim[5] = 128;
    A.x[6] = DUMat; A.W[6] = du_in_w + 256 * 128; A.bia[6] = du_in_b + 256; A.out[6] = vdu;   A.Kdim[6] = 128;
    A.x[7] = UUMat; A.W[7] = uu_in_w + 128 * 128; A.bia[7] = uu_in_b + 128; A.out[7] = kbase; A.Kdim[7] = 126;
    A.x[8] = UUMat; A.W[8] = uu_in_w + 256 * 128; A.bia[8] = uu_in_b + 256; A.out[8] = vbase; A.Kdim[8] = 126;
    A.CIMat = CIMat; A.cit = cit;
    A.dim_w = dim_w; A.dim_b = dim_b;
    A.uu_ow = uu_out_w; A.uu_ob = uu_out_b;
    A.ta_ow = ta_out_w; A.ta_ob = ta_out_b;
    A.du_ow = du_out_w; A.du_ob = du_out_b;
    A.Cuu = Cuu; A.Cta = Cta; A.Cdu = Cdu; A.bias_comb = bcomb;

    hipLaunchKernelGGL(pre_fused, dim3(PROJ_BLOCKS + TRANS_BLOCKS + COMB_BLOCKS), dim3(128), 0, stream, A);

    hipLaunchKernelGGL(attn256_pair, dim3(256, 2), dim3(256), 0, stream,
                       qta, kta, vta, ota, qdu, kdu, vdu, odu);

    hipLaunchKernelGGL(attn_uu_kernel, dim3(512), dim3(256), 0, stream,
                       qd, kbase, vbase, cit, uu_in_w, ouu);

    hipLaunchKernelGGL(epilogue_kernel, dim3(BL / 8), dim3(128), 0, stream,
                       ouu, ota, odu, Cuu, Cta, Cdu, bcomb, yy);

    hipLaunchKernelGGL(bn_kernel, dim3(8), dim3(256), 0, stream, yy, bn_g, bn_b, out);
}

// Round 5
// 212.461 us; speedup vs baseline: 2.0081x; 1.0559x over previous
//
#include <hip/hip_runtime.h>

// B=4, L=256, E=128, H=8, D=16, NU=512, NT=256. All I/O fp32.
// Pipeline: pre_fused (proj + CI transpose + weight-fold) -> attn256_pair ->
//           attn_uu -> memset(stats) -> epilogue(+bn stats atomics) -> bn_apply

struct PreArgs {
    const float* x[9]; const float* W[9]; const float* bia[9]; float* out[9];
    int Kdim[9]; int transNb[9];   // 0 = row-major out; else rows-per-b for [b][e][n] layout
    const float* CIMat; float* cit;
    const float* dim_w; const float* dim_b;
    const float* uu_ow; const float* uu_ob;
    const float* ta_ow; const float* ta_ob;
    const float* du_ow; const float* du_ob;
    float* Cuu; float* Cta; float* Cdu; float* bias_comb;
};

#define PRE_PROJ  704    // 7 tasks * 64 blocks + 2 tasks * 128 blocks (16 rows/block)
#define PRE_TRANS 1024
#define PRE_COMB  128

__global__ __launch_bounds__(128) void pre_fused(PreArgs A)
{
    __shared__ __align__(16) float smem[2048];
    int bid = blockIdx.x;
    int tid = threadIdx.x;

    if (bid < PRE_PROJ) {
        // ---- projection: out[m,e] = sum_k x[m,k]*W[e,k] + bias[e], 16 rows/block ----
        int task, mblk;
        if (bid < 448) { task = bid >> 6; mblk = bid & 63; }
        else { int r = bid - 448; task = 7 + (r >> 7); mblk = r & 127; }
        int e = tid;
        int Kd = A.Kdim[task];
        const float* x = A.x[task];
        int m0 = mblk * 16;
        float4* xs4 = (float4*)smem;
        if (Kd == 128) {
            const float4* x4 = (const float4*)(x + (size_t)m0 * 128);
#pragma unroll
            for (int i = 0; i < 4; ++i) xs4[tid + i * 128] = x4[tid + i * 128];
        } else {
#pragma unroll
            for (int r = 0; r < 16; ++r)
                smem[r * 128 + e] = (e < Kd) ? x[(size_t)(m0 + r) * Kd + e] : 0.f;
        }
        __syncthreads();
        const float4* w4 = (const float4*)(A.W[task] + (size_t)e * 128);
        float acc[16];
        float bv = A.bia[task][e];
#pragma unroll
        for (int r = 0; r < 16; ++r) acc[r] = bv;
#pragma unroll 4
        for (int c = 0; c < 32; ++c) {
            float4 w = w4[c];
#pragma unroll
            for (int r = 0; r < 16; ++r) {
                float4 xv = xs4[r * 32 + c];
                acc[r] += w.x * xv.x + w.y * xv.y + w.z * xv.z + w.w * xv.w;
            }
        }
        int nb = A.transNb[task];
        float* out = A.out[task];
        if (nb == 0) {
#pragma unroll
            for (int r = 0; r < 16; ++r) out[(size_t)(m0 + r) * 128 + e] = acc[r];
        } else {
            int b = m0 / nb, nloc = m0 - b * nb;
            float* o = out + ((size_t)b * 128 + e) * nb + nloc;
#pragma unroll
            for (int r = 0; r < 16; ++r) o[r] = acc[r];
        }

    } else if (bid < PRE_PROJ + PRE_TRANS) {
        // ---- CI transpose: cit[b][c][n] = CIMat[b][n][c] ----
        int tb = bid - PRE_PROJ;
        int b = tb >> 8, t = tb & 255;
        int n0 = (t >> 4) * 32, c0 = (t & 15) * 32;
        float (*tile)[33] = (float(*)[33])smem;
        int tx = tid & 31, ty = tid >> 5;
        const float* src = A.CIMat + (size_t)b * 262144;
        float* dst = A.cit + (size_t)b * 262144;
#pragma unroll
        for (int i = ty; i < 32; i += 4)
            tile[i][tx] = src[(size_t)(n0 + i) * 512 + c0 + tx];
        __syncthreads();
#pragma unroll
        for (int i = ty; i < 32; i += 4)
            dst[(size_t)(c0 + i) * 512 + n0 + tx] = tile[tx][i];

    } else {
        // ---- fold out-projections into dim projection ----
        float* ds = smem;
        float* red = smem + 384;
        int e = bid - PRE_PROJ - PRE_TRANS;
        int k = tid;
        ds[k]       = A.dim_w[(size_t)e * 384 + k];
        ds[128 + k] = A.dim_w[(size_t)e * 384 + 128 + k];
        ds[256 + k] = A.dim_w[(size_t)e * 384 + 256 + k];
        __syncthreads();
        float cu = 0.f, ct = 0.f, cd = 0.f;
#pragma unroll 4
        for (int j = 0; j < 128; ++j) {
            cu += ds[j]       * A.uu_ow[(size_t)j * 128 + k];
            ct += ds[128 + j] * A.ta_ow[(size_t)j * 128 + k];
            cd += ds[256 + j] * A.du_ow[(size_t)j * 128 + k];
        }
        A.Cuu[(size_t)e * 128 + k] = cu;
        A.Cta[(size_t)e * 128 + k] = ct;
        A.Cdu[(size_t)e * 128 + k] = cd;
        red[k] = ds[k] * A.uu_ob[k] + ds[128 + k] * A.ta_ob[k] + ds[256 + k] * A.du_ob[k];
        __syncthreads();
        for (int off = 64; off; off >>= 1) {
            if (k < off) red[k] += red[k + off];
            __syncthreads();
        }
        if (k == 0) A.bias_comb[e] = A.dim_b[e] + red[0];
    }
}

// ---- attn256: 2 heads + 8 query rows per block, N=256 keys. grid (512, 2) ----
__global__ __launch_bounds__(256) void attn256_pair(
    const float* __restrict__ q0, const float* __restrict__ kT0,
    const float* __restrict__ v0, float* __restrict__ o0,
    const float* __restrict__ q1, const float* __restrict__ kT1,
    const float* __restrict__ v1, float* __restrict__ o1)
{
    const float* q  = blockIdx.y ? q1 : q0;
    const float* kT = blockIdx.y ? kT1 : kT0;
    const float* v  = blockIdx.y ? v1 : v0;
    float* o        = blockIdx.y ? o1 : o0;
    int bx = blockIdx.x;
    int hg = bx & 3;              // head-pair 0..3
    int lt = (bx >> 2) & 31;      // l-tile 0..31 (8 rows each)
    int b  = bx >> 7;
    int l0 = lt * 8, bl0 = b * 256 + l0;
    int tid = threadIdx.x;

    __shared__ float qs[8 * 32];          // [l][dloc]
    __shared__ float sc[16 * 256];        // [(hloc*8+l)][n]
    __shared__ float den[16];

    {   // stage q slice
        int l = tid >> 5, d = tid & 31;
        qs[l * 32 + d] = q[(size_t)(bl0 + l) * 128 + hg * 32 + d];
    }
    __syncthreads();

    // ---- scores: lane <-> key n, coalesced kT reads ----
    {
        int n = tid;
        const float* kp = kT + ((size_t)b * 128 + hg * 32) * 256 + n;
        float acc[8][2];
#pragma unroll
        for (int l = 0; l < 8; ++l) { acc[l][0] = 0.f; acc[l][1] = 0.f; }
#pragma unroll 8
        for (int d = 0; d < 32; ++d) {
            float kv = kp[(size_t)d * 256];
            int hl = d >> 4;
#pragma unroll
            for (int l = 0; l < 8; ++l) acc[l][hl] += qs[l * 32 + d] * kv;
        }
#pragma unroll
        for (int hl = 0; hl < 2; ++hl)
#pragma unroll
            for (int l = 0; l < 8; ++l)
                sc[(hl * 8 + l) * 256 + n] = acc[l][hl] * 0.25f;
    }
    __syncthreads();

    // ---- softmax: 16 groups x 16 lanes ----
    {
        int g = tid >> 4, j = tid & 15;
        float* row = sc + g * 256;
        float mx = -1e30f;
#pragma unroll 4
        for (int n = j; n < 256; n += 16) mx = fmaxf(mx, row[n]);
#pragma unroll
        for (int off = 8; off; off >>= 1) mx = fmaxf(mx, __shfl_down(mx, off, 16));
        mx = __shfl(mx, 0, 16);
        float s = 0.f;
#pragma unroll 4
        for (int n = j; n < 256; n += 16) {
            float ev = __expf(row[n] - mx);
            row[n] = ev; s += ev;
        }
#pragma unroll
        for (int off = 8; off; off >>= 1) s += __shfl_down(s, off, 16);
        if (j == 0) den[g] = s;
    }
    __syncthreads();

    // ---- V pass: thread <-> (col, l) ----
    {
        int col = tid & 31, l = tid >> 5;
        int colglob = hg * 32 + col;
        int g = (col >> 4) * 8 + l;
        const float* vcol = v + (size_t)b * 256 * 128 + colglob;
        const float* p = sc + g * 256;
        float acc = 0.f;
#pragma unroll 4
        for (int n = 0; n < 256; ++n) acc += p[n] * vcol[(size_t)n * 128];
        o[(size_t)(bl0 + l) * 128 + colglob] = acc / den[g];
    }
}

// ---- attn_uu: 2 heads + 4 query rows per block, N=512, rank-2 ci correction ----
__global__ __launch_bounds__(256) void attn_uu_kernel(
    const float* __restrict__ qd, const float* __restrict__ kT,
    const float* __restrict__ vbase, const float* __restrict__ cit,
    const float* __restrict__ in_w, float* __restrict__ o)
{
    int bx = blockIdx.x;
    int hg = bx & 3;              // head-pair
    int lt = (bx >> 2) & 63;      // l-tile (4 rows)
    int b  = bx >> 8;
    int l0 = lt * 4, bl0 = b * 256 + l0;
    int tid = threadIdx.x;

    __shared__ float qs[4 * 32];          // [l][dloc]
    __shared__ float sc[8 * 512];         // [(hloc*4+l)][n]
    __shared__ __align__(16) float ci0s[4 * 512];   // [l][n]
    __shared__ __align__(16) float ci1s[4 * 512];
    __shared__ float qkA[8], qkB[8];      // [hloc*4+l]
    __shared__ float den[8], hs0[8], hs1[8];
    __shared__ float vpart[2 * 128];

    if (tid < 128) {
        int l = tid >> 5, d = tid & 31;
        qs[l * 32 + d] = qd[(size_t)(bl0 + l) * 128 + hg * 32 + d];
    }
    {   // ci rows are contiguous in cit: rows [l0..l0+3] and [256+l0..256+l0+3]
        const float4* s0 = (const float4*)(cit + ((size_t)b * 512 + l0) * 512);
        const float4* s1 = (const float4*)(cit + ((size_t)b * 512 + 256 + l0) * 512);
        float4* d0 = (float4*)ci0s;
        float4* d1 = (float4*)ci1s;
        d0[tid] = s0[tid];       d0[tid + 256] = s0[tid + 256];
        d1[tid] = s1[tid];       d1[tid + 256] = s1[tid + 256];
    }
    __syncthreads();
    if (tid < 8) {
        int hl = tid >> 2, l = tid & 3;
        float a = 0.f, c = 0.f;
#pragma unroll
        for (int d = 0; d < 16; ++d) {
            float qv = qs[l * 32 + hl * 16 + d];
            int wr = 128 + hg * 32 + hl * 16 + d;
            a += qv * in_w[(size_t)wr * 128 + 126];
            c += qv * in_w[(size_t)wr * 128 + 127];
        }
        qkA[tid] = a; qkB[tid] = c;
    }
    __syncthreads();

    // ---- scores: lane <-> n (two chunks), coalesced kT reads ----
    {
        const float* kp = kT + ((size_t)b * 128 + hg * 32) * 512 + tid;
        float acc[2][4][2];
#pragma unroll
        for (int r = 0; r < 2; ++r)
#pragma unroll
            for (int l = 0; l < 4; ++l) { acc[r][l][0] = 0.f; acc[r][l][1] = 0.f; }
#pragma unroll 8
        for (int d = 0; d < 32; ++d) {
            float kv0 = kp[(size_t)d * 512];
            float kv1 = kp[(size_t)d * 512 + 256];
            int hl = d >> 4;
#pragma unroll
            for (int l = 0; l < 4; ++l) {
                float qv = qs[l * 32 + d];
                acc[0][l][hl] += qv * kv0;
                acc[1][l][hl] += qv * kv1;
            }
        }
#pragma unroll
        for (int r = 0; r < 2; ++r) {
            int n = tid + r * 256;
#pragma unroll
            for (int l = 0; l < 4; ++l) {
                float c0 = ci0s[l * 512 + n], c1 = ci1s[l * 512 + n];
#pragma unroll
                for (int hl = 0; hl < 2; ++hl) {
                    int g = hl * 4 + l;
                    sc[g * 512 + n] = (acc[r][l][hl] + c0 * qkA[g] + c1 * qkB[g]) * 0.25f;
                }
            }
        }
    }
    __syncthreads();

    // ---- softmax + ci-weighted sums: 8 groups x 32 lanes ----
    {
        int g = tid >> 5, j = tid & 31;
        int l = g & 3;
        float* row = sc + g * 512;
        const float* c0r = ci0s + l * 512;
        const float* c1r = ci1s + l * 512;
        float mx = -1e30f;
#pragma unroll 4
        for (int n = j; n < 512; n += 32) mx = fmaxf(mx, row[n]);
#pragma unroll
        for (int off = 16; off; off >>= 1) mx = fmaxf(mx, __shfl_down(mx, off, 32));
        mx = __shfl(mx, 0, 32);
        float s = 0.f, a0 = 0.f, a1 = 0.f;
#pragma unroll 4
        for (int n = j; n < 512; n += 32) {
            float ev = __expf(row[n] - mx);
            row[n] = ev;
            s += ev; a0 += ev * c0r[n]; a1 += ev * c1r[n];
        }
#pragma unroll
        for (int off = 16; off; off >>= 1) {
            s  += __shfl_down(s, off, 32);
            a0 += __shfl_down(a0, off, 32);
            a1 += __shfl_down(a1, off, 32);
        }
        if (j == 0) { den[g] = s; hs0[g] = a0; hs1[g] = a1; }
    }
    __syncthreads();

    // ---- V pass: thread <-> (col, l, n-half) ----
    {
        int col = tid & 31, l = (tid >> 5) & 3, half = tid >> 7;
        int colglob = hg * 32 + col;
        int g = (col >> 4) * 4 + l;
        const float* vcol = vbase + ((size_t)b * 512 + half * 256) * 128 + colglob;
        const float* p = sc + g * 512 + half * 256;
        float acc = 0.f;
#pragma unroll 4
        for (int n = 0; n < 256; ++n) acc += p[n] * vcol[(size_t)n * 128];
        vpart[half * 128 + (tid & 127)] = acc;
    }
    __syncthreads();
    if (tid < 128) {
        int col = tid & 31, l = tid >> 5;
        int colglob = hg * 32 + col;
        int g = (col >> 4) * 4 + l;
        float sum = vpart[tid] + vpart[128 + tid];
        float wv126 = in_w[(size_t)(256 + colglob) * 128 + 126];
        float wv127 = in_w[(size_t)(256 + colglob) * 128 + 127];
        o[(size_t)(bl0 + l) * 128 + colglob] =
            (sum + hs0[g] * wv126 + hs1[g] * wv127) / den[g];
    }
}

// ---- epilogue: y = Cuu@ouu + Cta@ota + Cdu@odu + bias_comb; + BN stat atomics ----
__global__ __launch_bounds__(128) void epilogue_kernel(
    const float* __restrict__ ouu, const float* __restrict__ ota,
    const float* __restrict__ odu,
    const float* __restrict__ Cuu, const float* __restrict__ Cta,
    const float* __restrict__ Cdu, const float* __restrict__ bias_comb,
    float* __restrict__ y, float* __restrict__ gsum, float* __restrict__ gsum2)
{
    __shared__ __align__(16) float xs[4 * 384];
    int m0 = blockIdx.x * 4;
    int e = threadIdx.x;
#pragma unroll
    for (int r = 0; r < 4; ++r) {
        xs[r * 384 + e]       = ouu[(size_t)(m0 + r) * 128 + e];
        xs[r * 384 + 128 + e] = ota[(size_t)(m0 + r) * 128 + e];
        xs[r * 384 + 256 + e] = odu[(size_t)(m0 + r) * 128 + e];
    }
    __syncthreads();
    const float4* cu4 = (const float4*)(Cuu + (size_t)e * 128);
    const float4* ct4 = (const float4*)(Cta + (size_t)e * 128);
    const float4* cd4 = (const float4*)(Cdu + (size_t)e * 128);
    const float4* xs4 = (const float4*)xs;   // row pitch 96 float4
    float acc[4];
    float bc = bias_comb[e];
#pragma unroll
    for (int r = 0; r < 4; ++r) acc[r] = bc;
#pragma unroll 4
    for (int c = 0; c < 32; ++c) {
        float4 a = cu4[c], bb = ct4[c], d = cd4[c];
#pragma unroll
        for (int r = 0; r < 4; ++r) {
            float4 xu = xs4[r * 96 + c];
            float4 xt = xs4[r * 96 + 32 + c];
            float4 xd = xs4[r * 96 + 64 + c];
            acc[r] += a.x * xu.x + a.y * xu.y + a.z * xu.z + a.w * xu.w
                    + bb.x * xt.x + bb.y * xt.y + bb.z * xt.z + bb.w * xt.w
                    + d.x * xd.x + d.y * xd.y + d.z * xd.z + d.w * xd.w;
        }
    }
    float s = 0.f, s2 = 0.f;
#pragma unroll
    for (int r = 0; r < 4; ++r) {
        y[(size_t)(m0 + r) * 128 + e] = acc[r];
        s += acc[r]; s2 += acc[r] * acc[r];
    }
    atomicAdd(&gsum[e], s);
    atomicAdd(&gsum2[e], s2);
}

// ---- bn_apply: (y - mean) * rsqrt(var+eps) * g + b, ReLU. 128 blocks x 256 thr ----
__global__ __launch_bounds__(256) void bn_apply(
    const float* __restrict__ y, const float* __restrict__ gsum,
    const float* __restrict__ gsum2, const float* __restrict__ gamma,
    const float* __restrict__ beta, float* __restrict__ out)
{
    int gid = blockIdx.x * 256 + threadIdx.x;      // float4 index, 32768 total
    int c0 = (gid & 31) * 4;
    float4 v = ((const float4*)y)[gid];
    float r[4] = { v.x, v.y, v.z, v.w };
#pragma unroll
    for (int k = 0; k < 4; ++k) {
        int c = c0 + k;
        float mean = gsum[c] * (1.f / 1024.f);
        float var = gsum2[c] * (1.f / 1024.f) - mean * mean;
        float inv = rsqrtf(var + 1e-5f);
        r[k] = fmaxf((r[k] - mean) * inv * gamma[c] + beta[c], 0.f);
    }
    float4 ov = { r[0], r[1], r[2], r[3] };
    ((float4*)out)[gid] = ov;
}

extern "C" void kernel_launch(void* const* d_in, const int* in_sizes, int n_in,
                              void* d_out, int out_size, void* d_ws, size_t ws_size,
                              hipStream_t stream)
{
    (void)in_sizes; (void)n_in; (void)out_size; (void)ws_size;
    const float* UUMat    = (const float*)d_in[0];
    const float* DUMat    = (const float*)d_in[1];
    const float* TAMat    = (const float*)d_in[2];
    const float* CIMat    = (const float*)d_in[3];
    const float* uu_in_w  = (const float*)d_in[4];
    const float* uu_in_b  = (const float*)d_in[5];
    const float* uu_out_w = (const float*)d_in[6];
    const float* uu_out_b = (const float*)d_in[7];
    const float* ta_in_w  = (const float*)d_in[8];
    const float* ta_in_b  = (const float*)d_in[9];
    const float* ta_out_w = (const float*)d_in[10];
    const float* ta_out_b = (const float*)d_in[11];
    const float* du_in_w  = (const float*)d_in[12];
    const float* du_in_b  = (const float*)d_in[13];
    const float* du_out_w = (const float*)d_in[14];
    const float* du_out_b = (const float*)d_in[15];
    const float* dim_w    = (const float*)d_in[16];
    const float* dim_b    = (const float*)d_in[17];
    const float* bn_g     = (const float*)d_in[18];
    const float* bn_b     = (const float*)d_in[19];
    float* out = (float*)d_out;

    const int BL = 1024, BN = 2048;
    float* ws = (float*)d_ws;
    float* cit    = ws; ws += (size_t)4 * 512 * 512;
    float* qd     = ws; ws += (size_t)BL * 128;
    float* kbaseT = ws; ws += (size_t)BN * 128;   // [b][128][512]
    float* vbase  = ws; ws += (size_t)BN * 128;
    float* qta    = ws; ws += (size_t)BL * 128;
    float* ktaT   = ws; ws += (size_t)BL * 128;   // [b][128][256]
    float* vta    = ws; ws += (size_t)BL * 128;
    float* qdu    = ws; ws += (size_t)BL * 128;
    float* kduT   = ws; ws += (size_t)BL * 128;   // [b][128][256]
    float* vdu    = ws; ws += (size_t)BL * 128;
    float* ouu    = ws; ws += (size_t)BL * 128;
    float* ota    = ws; ws += (size_t)BL * 128;
    float* odu    = ws; ws += (size_t)BL * 128;
    float* yy     = ws; ws += (size_t)BL * 128;
    float* Cuu    = ws; ws += 128 * 128;
    float* Cta    = ws; ws += 128 * 128;
    float* Cdu    = ws; ws += 128 * 128;
    float* bcomb  = ws; ws += 128;
    float* gsum   = ws; ws += 128;
    float* gsum2  = ws; ws += 128;

    PreArgs A;
    A.x[0] = DUMat; A.W[0] = uu_in_w;             A.bia[0] = uu_in_b;       A.out[0] = qd;     A.Kdim[0] = 128; A.transNb[0] = 0;
    A.x[1] = DUMat; A.W[1] = ta_in_w;             A.bia[1] = ta_in_b;       A.out[1] = qta;    A.Kdim[1] = 128; A.transNb[1] = 0;
    A.x[2] = TAMat; A.W[2] = ta_in_w + 128 * 128; A.bia[2] = ta_in_b + 128; A.out[2] = ktaT;   A.Kdim[2] = 128; A.transNb[2] = 256;
    A.x[3] = TAMat; A.W[3] = ta_in_w + 256 * 128; A.bia[3] = ta_in_b + 256; A.out[3] = vta;    A.Kdim[3] = 128; A.transNb[3] = 0;
    A.x[4] = DUMat; A.W[4] = du_in_w;             A.bia[4] = du_in_b;       A.out[4] = qdu;    A.Kdim[4] = 128; A.transNb[4] = 0;
    A.x[5] = DUMat; A.W[5] = du_in_w + 128 * 128; A.bia[5] = du_in_b + 128; A.out[5] = kduT;   A.Kdim[5] = 128; A.transNb[5] = 256;
    A.x[6] = DUMat; A.W[6] = du_in_w + 256 * 128; A.bia[6] = du_in_b + 256; A.out[6] = vdu;    A.Kdim[6] = 128; A.transNb[6] = 0;
    A.x[7] = UUMat; A.W[7] = uu_in_w + 128 * 128; A.bia[7] = uu_in_b + 128; A.out[7] = kbaseT; A.Kdim[7] = 126; A.transNb[7] = 512;
    A.x[8] = UUMat; A.W[8] = uu_in_w + 256 * 128; A.bia[8] = uu_in_b + 256; A.out[8] = vbase;  A.Kdim[8] = 126; A.transNb[8] = 0;
    A.CIMat = CIMat; A.cit = cit;
    A.dim_w = dim_w; A.dim_b = dim_b;
    A.uu_ow = uu_out_w; A.uu_ob = uu_out_b;
    A.ta_ow = ta_out_w; A.ta_ob = ta_out_b;
    A.du_ow = du_out_w; A.du_ob = du_out_b;
    A.Cuu = Cuu; A.Cta = Cta; A.Cdu = Cdu; A.bias_comb = bcomb;

    hipLaunchKernelGGL(pre_fused, dim3(PRE_PROJ + PRE_TRANS + PRE_COMB), dim3(128), 0, stream, A);

    hipLaunchKernelGGL(attn256_pair, dim3(512, 2), dim3(256), 0, stream,
                       qta, ktaT, vta, ota, qdu, kduT, vdu, odu);

    hipLaunchKernelGGL(attn_uu_kernel, dim3(1024), dim3(256), 0, stream,
                       qd, kbaseT, vbase, cit, uu_in_w, ouu);

    hipMemsetAsync(gsum, 0, 2 * 128 * sizeof(float), stream);

    hipLaunchKernelGGL(epilogue_kernel, dim3(256), dim3(128), 0, stream,
                       ouu, ota, odu, Cuu, Cta, Cdu, bcomb, yy, gsum, gsum2);

    hipLaunchKernelGGL(bn_apply, dim3(128), dim3(256), 0, stream,
                       yy, gsum, gsum2, bn_g, bn_b, out);
}